// Round 5
// baseline (500.605 us; speedup 1.0000x reference)
//
#include <hip/hip_runtime.h>

#define EMBED 1024
#define BATCH 4
#define SEQ   4096
#define ROWS  (BATCH*SEQ)   // 16384
#define CAP   128           // candidate slots per row (r3-r12 proven)
#define TSCAN_U 1600.0f     // scan margin, unscaled (50 scaled) — r12-proven passing
#define TRES  75.0f         // rescore margin, scaled logits (proven)

typedef __attribute__((ext_vector_type(8))) short bf16x8;
typedef __attribute__((ext_vector_type(4))) float f32x4;

static __device__ __forceinline__ unsigned short f2bf(float x) {
    unsigned u = __float_as_uint(x);
    u = (u + 0x7fffu + ((u >> 16) & 1u)) >> 16;
    return (unsigned short)u;
}
static __device__ __forceinline__ float bf2f(unsigned short h) {
    return __uint_as_float(((unsigned)h) << 16);
}
static __device__ __forceinline__ void split2(float x, unsigned short& hi, unsigned short& lo) {
    hi = f2bf(x);
    lo = f2bf(x - bf2f(hi));
}

// ---- async global->LDS staging, 128x32-short tile, 4-segment swizzle (r3-proven, 0 conflicts) ----
static __device__ __forceinline__ void stage_tile(unsigned short (*lds)[32],
                                                  const unsigned short* gbase,
                                                  int wave, int lane) {
#pragma unroll
    for (int c = 0; c < 2; c++) {
        int L = wave * 128 + c * 64 + lane;   // linear segment index 0..511
        int r = L >> 2, s = L & 3;
        int g = (s - (r >> 1)) & 3;
        __builtin_amdgcn_global_load_lds(
            (const __attribute__((address_space(1))) unsigned int*)(gbase + (size_t)r * EMBED + g * 8),
            (__attribute__((address_space(3))) unsigned int*)(&lds[r][s * 8]),
            16, 0, 0);
    }
}
static __device__ __forceinline__ bf16x8 read_frag(const unsigned short (*lds)[32], int r, int kq) {
    int s = ((kq >> 3) + (r >> 1)) & 3;
    return *(const bf16x8*)&lds[r][s * 8];
}

// ---------------- prep: wv_bar[i] = mean_d Wv[i][d] ----------------
__global__ void k_wvbar(const float* __restrict__ Wv, float* __restrict__ wvbar) {
    int r = blockIdx.x, t = threadIdx.x;
    float s = 0.f;
    for (int c = t; c < EMBED; c += 256) s += Wv[(size_t)r * EMBED + c];
    for (int d = 1; d < 64; d <<= 1) s += __shfl_xor(s, d);
    __shared__ float ws_[4];
    if ((t & 63) == 0) ws_[t >> 6] = s;
    __syncthreads();
    if (t == 0) wvbar[r] = (ws_[0] + ws_[1] + ws_[2] + ws_[3]) * (1.0f / EMBED);
}

// ---------------- prep: row split + vmean + cnt zeroing (fused, one X read) ----------------
__global__ __launch_bounds__(256) void k_xsplit_vmean(
    const float* __restrict__ X, const float* __restrict__ wvbar,
    unsigned short* __restrict__ Xhi, unsigned short* __restrict__ Xlo,
    float* __restrict__ vmean, int* __restrict__ cnt) {
    int row = blockIdx.x, t = threadIdx.x;
    float4 x4 = *(const float4*)(X + (size_t)row * EMBED + t * 4);
    float4 w4 = *(const float4*)(wvbar + t * 4);
    ushort4 h, l;
    split2(x4.x, h.x, l.x); split2(x4.y, h.y, l.y);
    split2(x4.z, h.z, l.z); split2(x4.w, h.w, l.w);
    *(ushort4*)(Xhi + (size_t)row * EMBED + t * 4) = h;
    *(ushort4*)(Xlo + (size_t)row * EMBED + t * 4) = l;
    float s = x4.x * w4.x + x4.y * w4.y + x4.z * w4.z + x4.w * w4.w;
    for (int d = 1; d < 64; d <<= 1) s += __shfl_xor(s, d);
    __shared__ float ws_[4];
    if ((t & 63) == 0) ws_[t >> 6] = s;
    __syncthreads();
    if (t == 0) { vmean[row] = ws_[0] + ws_[1] + ws_[2] + ws_[3]; cnt[row] = 0; }
}

// ---------------- split-bf16 GEMM: C[row][col] = sum_k A[row][k]*B[col][k] ----------------
__global__ __launch_bounds__(256) void k_gemm3(
    const unsigned short* __restrict__ Ahi, const unsigned short* __restrict__ Alo,
    const unsigned short* __restrict__ BThi, const unsigned short* __restrict__ BTlo,
    unsigned short* __restrict__ Chi, unsigned short* __restrict__ Clo) {
    __shared__ unsigned short Ah[128][32], Al[128][32], Bh[128][32], Bl[128][32];
    int bx = blockIdx.x;
    int bm = bx >> 3, bn = bx & 7;   // bn == XCD id under round-robin: B-tiles L2-local
    int tid = threadIdx.x, wave = tid >> 6, lane = tid & 63;
    int wm = (wave >> 1) * 64, wn = (wave & 1) * 64;
    int mrow = lane & 15, kq = (lane >> 4) * 8;

    f32x4 zero = {0.f, 0.f, 0.f, 0.f};
    f32x4 acc[4][4];
    for (int a = 0; a < 4; a++) for (int b = 0; b < 4; b++) acc[a][b] = zero;

    const unsigned short* Abase_h = Ahi + (size_t)(bm * 128) * EMBED;
    const unsigned short* Abase_l = Alo + (size_t)(bm * 128) * EMBED;
    const unsigned short* Bbase_h = BThi + (size_t)(bn * 128) * EMBED;
    const unsigned short* Bbase_l = BTlo + (size_t)(bn * 128) * EMBED;

    for (int k0 = 0; k0 < EMBED; k0 += 32) {
        __syncthreads();
        stage_tile(Ah, Abase_h + k0, wave, lane);
        stage_tile(Al, Abase_l + k0, wave, lane);
        stage_tile(Bh, Bbase_h + k0, wave, lane);
        stage_tile(Bl, Bbase_l + k0, wave, lane);
        __syncthreads();
        bf16x8 ah[4], al[4], bh[4], bl[4];
#pragma unroll
        for (int t = 0; t < 4; t++) {
            ah[t] = read_frag(Ah, wm + t * 16 + mrow, kq);
            al[t] = read_frag(Al, wm + t * 16 + mrow, kq);
            bh[t] = read_frag(Bh, wn + t * 16 + mrow, kq);
            bl[t] = read_frag(Bl, wn + t * 16 + mrow, kq);
        }
#pragma unroll
        for (int mt = 0; mt < 4; mt++)
#pragma unroll
            for (int nt = 0; nt < 4; nt++) {
                acc[mt][nt] = __builtin_amdgcn_mfma_f32_16x16x32_bf16(ah[mt], bh[nt], acc[mt][nt], 0, 0, 0);
                acc[mt][nt] = __builtin_amdgcn_mfma_f32_16x16x32_bf16(ah[mt], bl[nt], acc[mt][nt], 0, 0, 0);
                acc[mt][nt] = __builtin_amdgcn_mfma_f32_16x16x32_bf16(al[mt], bh[nt], acc[mt][nt], 0, 0, 0);
            }
    }
#pragma unroll
    for (int mt = 0; mt < 4; mt++)
#pragma unroll
        for (int nt = 0; nt < 4; nt++)
#pragma unroll
            for (int i = 0; i < 4; i++) {
                int row = bm * 128 + wm + mt * 16 + (lane >> 4) * 4 + i;
                int col = bn * 128 + wn + nt * 16 + (lane & 15);
                unsigned short h, l; split2(acc[mt][nt][i], h, l);
                Chi[(size_t)row * EMBED + col] = h;
                Clo[(size_t)row * EMBED + col] = l;
            }
}

// ---------------- scan: 256q x 256k block, 512 threads, 8 waves (2q x 4k), counted-vmcnt ----------------
// r13-r16 ledger: every 2-barrier-template variant lands 215-230us. Accounting: MFMA 55us +
// LDS ~90us + HBM ~30us ~= 215us measured => pipes SERIALIZED (m233's 2-phase stall signature;
// our 640 TF ~= m233's 607). Fix per m218/m201: counted vmcnt so staging rides ACROSS barriers.
// Design: BK=32 staging units, 4-deep LDS rotation (132 KB), ONE barrier per K-step,
// s_waitcnt vmcnt(8) -> the 4 loads issued 3 steps ago complete; current + next 2 units stay
// in flight. Register discipline (r14 lesson): per-lane stage offset collapses to ONE (goff,
// loff) pair — the 2nd load's delta is compile-time ((r+128)>>1 shifts g by 64 == 0 mod 4);
// static buffer names; __launch_bounds__(512,2) caps 256 VGPR (acc[8][4]=128 + ~70 arch).
// Buffer hazard audit: step t stages unit (t+3)&3 == unit computed at t-1; lgkmcnt(0)+barrier
// at top of t guarantees all waves' ds_reads of it completed. setprio wraps the 32-MFMA
// cluster (phase role-split now exists -> T5 gate). Epilogue: row max combined across all 4
// k-waves (256-key window). Window-size safety: capture set is always a superset of
// {s >= global_max - TSCAN_U} for ANY window (window max <= global max); larger windows only
// REDUCE candidate counts -> CAP strictly safer than the proven 128-window config.
static __device__ __forceinline__ void stage_unit(
    unsigned short (*Tu)[32], unsigned short (*Xu)[32],
    const unsigned short* Tg, const unsigned short* Xg, int goff, int loff) {
    __builtin_amdgcn_global_load_lds(
        (const __attribute__((address_space(1))) unsigned int*)(Tg + goff),
        (__attribute__((address_space(3))) unsigned int*)((unsigned short*)Tu + loff), 16, 0, 0);
    __builtin_amdgcn_global_load_lds(
        (const __attribute__((address_space(1))) unsigned int*)(Tg + goff + 128 * EMBED),
        (__attribute__((address_space(3))) unsigned int*)((unsigned short*)Tu + loff + 128 * 32), 16, 0, 0);
    __builtin_amdgcn_global_load_lds(
        (const __attribute__((address_space(1))) unsigned int*)(Xg + goff),
        (__attribute__((address_space(3))) unsigned int*)((unsigned short*)Xu + loff), 16, 0, 0);
    __builtin_amdgcn_global_load_lds(
        (const __attribute__((address_space(1))) unsigned int*)(Xg + goff + 128 * EMBED),
        (__attribute__((address_space(3))) unsigned int*)((unsigned short*)Xu + loff + 128 * 32), 16, 0, 0);
}

template<int NW>
static __device__ __forceinline__ void wait_barrier() {
    if constexpr (NW == 8)      asm volatile("s_waitcnt vmcnt(8) lgkmcnt(0)" ::: "memory");
    else if constexpr (NW == 4) asm volatile("s_waitcnt vmcnt(4) lgkmcnt(0)" ::: "memory");
    else                        asm volatile("s_waitcnt vmcnt(0) lgkmcnt(0)" ::: "memory");
    __builtin_amdgcn_s_barrier();
    asm volatile("" ::: "memory");   // ds_reads of the next step may not hoist above the barrier
}

static __device__ __forceinline__ void scan_mfma(
    const unsigned short (*Tu)[32], const unsigned short (*Xu)[32],
    int wq, int wk, int mrow, int kq, f32x4 (&acc)[8][4]) {
    bf16x8 ah[8], bh[4];
#pragma unroll
    for (int a = 0; a < 8; a++) ah[a] = read_frag(Tu, wq + a * 16 + mrow, kq);
#pragma unroll
    for (int n = 0; n < 4; n++) bh[n] = read_frag(Xu, wk + n * 16 + mrow, kq);
    __builtin_amdgcn_s_setprio(1);
#pragma unroll
    for (int a = 0; a < 8; a++)
#pragma unroll
        for (int n = 0; n < 4; n++)
            acc[a][n] = __builtin_amdgcn_mfma_f32_16x16x32_bf16(ah[a], bh[n], acc[a][n], 0, 0, 0);
    __builtin_amdgcn_s_setprio(0);
}

__global__ __launch_bounds__(512, 2) void k_scan(
    const unsigned short* __restrict__ Thi, const unsigned short* __restrict__ Xhi,
    int* __restrict__ cnt, int2* __restrict__ cand) {
    __shared__ unsigned short Tt[4][256][32];   // 64 KB
    __shared__ unsigned short Xt[4][256][32];   // 64 KB
    __shared__ float rowmax_[4][2][128];        // 4 KB

    int bid = blockIdx.x;            // 0..1023
    int x   = bid & 7;               // XCD id: owns 2 fixed 256-key super-tiles per batch
    int i   = bid >> 3;              // 0..127
    int kb2 = x * 2 + (i & 1);       // 0..15
    int qb  = (i >> 1) & 15;         // 0..15
    int b   = i >> 5;                // 0..3
    int tid = threadIdx.x, wave = tid >> 6, lane = tid & 63;
    int wr = wave >> 2, wc = wave & 3;
    int wq = wr * 128, wk = wc * 64;
    int mrow = lane & 15, kq = (lane >> 4) * 8;
    size_t qrow0 = (size_t)b * SEQ + (size_t)qb * 256;
    size_t krow0 = (size_t)b * SEQ + (size_t)kb2 * 256;
    const unsigned short* Tbase = Thi + qrow0 * EMBED;
    const unsigned short* Xbase = Xhi + krow0 * EMBED;

    // per-lane staging offsets (512-thread linear index; 4-segment swizzle, r3-proven)
    int r = tid >> 2, s = tid & 3, g = (s - (r >> 1)) & 3;
    int goff = r * EMBED + g * 8;    // global element offset within a 256x32 unit
    int loff = r * 32 + s * 8;       // LDS short offset (= tid*8: linear in lane, 16B stride)

    f32x4 zero = {0.f, 0.f, 0.f, 0.f};
    f32x4 acc[8][4];
#pragma unroll
    for (int a = 0; a < 8; a++)
#pragma unroll
        for (int n = 0; n < 4; n++) acc[a][n] = zero;

    // prologue: stage K-steps 0,1,2 into units 0,1,2 (12 loads in flight)
    stage_unit(Tt[0], Xt[0], Tbase,      Xbase,      goff, loff);
    stage_unit(Tt[1], Xt[1], Tbase + 32, Xbase + 32, goff, loff);
    stage_unit(Tt[2], Xt[2], Tbase + 64, Xbase + 64, goff, loff);

    // steady state: one barrier + one vmcnt(8) per K-step; stage runs 3 steps ahead
    for (int t = 0; t < 28; t += 4) {
        const unsigned short* Tk = Tbase + (size_t)t * 32;
        const unsigned short* Xk = Xbase + (size_t)t * 32;
        wait_barrier<8>(); stage_unit(Tt[3], Xt[3], Tk +  96, Xk +  96, goff, loff);
        scan_mfma(Tt[0], Xt[0], wq, wk, mrow, kq, acc);
        wait_barrier<8>(); stage_unit(Tt[0], Xt[0], Tk + 128, Xk + 128, goff, loff);
        scan_mfma(Tt[1], Xt[1], wq, wk, mrow, kq, acc);
        wait_barrier<8>(); stage_unit(Tt[1], Xt[1], Tk + 160, Xk + 160, goff, loff);
        scan_mfma(Tt[2], Xt[2], wq, wk, mrow, kq, acc);
        wait_barrier<8>(); stage_unit(Tt[2], Xt[2], Tk + 192, Xk + 192, goff, loff);
        scan_mfma(Tt[3], Xt[3], wq, wk, mrow, kq, acc);
    }
    // tail: t=28 (stage k=31), then drain 29/30/31 with shrinking counts
    {
        const unsigned short* Tk = Tbase + 28 * 32;
        const unsigned short* Xk = Xbase + 28 * 32;
        wait_barrier<8>(); stage_unit(Tt[3], Xt[3], Tk + 96, Xk + 96, goff, loff);
        scan_mfma(Tt[0], Xt[0], wq, wk, mrow, kq, acc);
        wait_barrier<8>(); scan_mfma(Tt[1], Xt[1], wq, wk, mrow, kq, acc);
        wait_barrier<4>(); scan_mfma(Tt[2], Xt[2], wq, wk, mrow, kq, acc);
        wait_barrier<0>(); scan_mfma(Tt[3], Xt[3], wq, wk, mrow, kq, acc);
    }

    // ---- epilogue pass 1: per-row max over this wave's 64 keys -> LDS exchange ----
#pragma unroll
    for (int a = 0; a < 8; a++)
#pragma unroll
        for (int i2 = 0; i2 < 4; i2++) {
            float v = -INFINITY;
#pragma unroll
            for (int n = 0; n < 4; n++) v = fmaxf(v, acc[a][n][i2]);
#pragma unroll
            for (int d = 1; d < 16; d <<= 1) v = fmaxf(v, __shfl_xor(v, d));
            if ((lane & 15) == 0)
                rowmax_[wc][wr][a * 16 + (lane >> 4) * 4 + i2] = v;
        }
    __syncthreads();
    // ---- epilogue pass 2: threshold over the block's FULL 256 keys; emit candidates ----
#pragma unroll
    for (int a = 0; a < 8; a++)
#pragma unroll
        for (int i2 = 0; i2 < 4; i2++) {
            int lr = a * 16 + (lane >> 4) * 4 + i2;
            float th = fmaxf(fmaxf(rowmax_[0][wr][lr], rowmax_[1][wr][lr]),
                             fmaxf(rowmax_[2][wr][lr], rowmax_[3][wr][lr])) - TSCAN_U;
            int grow = (int)qrow0 + wq + lr;
#pragma unroll
            for (int n = 0; n < 4; n++) {
                float sc = acc[a][n][i2];
                if (sc >= th) {
                    int gcol = (int)krow0 + wk + n * 16 + (lane & 15);
                    int idx = atomicAdd(&cnt[grow], 1);
                    if (idx < CAP)
                        cand[(size_t)grow * CAP + idx] = make_int2(gcol, __float_as_int(sc * 0.03125f));
                }
            }
        }
}

// ---------------- rescore: 4 rows per block, one wave per row, barrier-free ----------------
__global__ __launch_bounds__(256) void k_rescore(
    const unsigned short* __restrict__ Thi, const unsigned short* __restrict__ Tlo,
    const float* __restrict__ X, const float* __restrict__ vmean,
    const int* __restrict__ cnt, const int2* __restrict__ cand,
    float* __restrict__ out) {
    int wave = threadIdx.x >> 6, lane = threadIdx.x & 63;
    int row = blockIdx.x * 4 + wave;
    int c = cnt[row]; if (c > CAP) c = CAP;
    const int2* cl = cand + (size_t)row * CAP;

    float smax = -INFINITY;
    for (int j = lane; j < c; j += 64) smax = fmaxf(smax, __int_as_float(cl[j].y));
    for (int d = 1; d < 64; d <<= 1) smax = fmaxf(smax, __shfl_xor(smax, d));
    float th = smax - TRES;

    float q[16];
    {
        const unsigned short* qh = Thi + (size_t)row * EMBED + lane * 16;
        const unsigned short* ql = Tlo + (size_t)row * EMBED + lane * 16;
        bf16x8 h0 = *(const bf16x8*)qh, h1 = *(const bf16x8*)(qh + 8);
        bf16x8 l0 = *(const bf16x8*)ql, l1 = *(const bf16x8*)(ql + 8);
#pragma unroll
        for (int i = 0; i < 8; i++) {
            q[i]     = bf2f((unsigned short)h0[i]) + bf2f((unsigned short)l0[i]);
            q[i + 8] = bf2f((unsigned short)h1[i]) + bf2f((unsigned short)l1[i]);
        }
    }

    __shared__ int   sm_[4][CAP];
    __shared__ float sl_[4][CAP];
    __shared__ int   ns_[4];
    if (lane == 0) ns_[wave] = 0;
    for (int j = lane; j < c; j += 64) {
        int2 p = cl[j];
        if (__int_as_float(p.y) >= th) {
            int idx = atomicAdd(&ns_[wave], 1);
            sm_[wave][idx] = p.x;
        }
    }
    int ns = ns_[wave];
    for (int t = 0; t < ns; t++) {
        int m = sm_[wave][t];
        const float* xr = X + (size_t)m * EMBED + lane * 16;
        float4 a0 = *(const float4*)(xr);
        float4 a1 = *(const float4*)(xr + 4);
        float4 a2 = *(const float4*)(xr + 8);
        float4 a3 = *(const float4*)(xr + 12);
        float dp = q[0]*a0.x + q[1]*a0.y + q[2]*a0.z + q[3]*a0.w
                 + q[4]*a1.x + q[5]*a1.y + q[6]*a1.z + q[7]*a1.w
                 + q[8]*a2.x + q[9]*a2.y + q[10]*a2.z + q[11]*a2.w
                 + q[12]*a3.x + q[13]*a3.y + q[14]*a3.z + q[15]*a3.w;
        for (int d = 1; d < 64; d <<= 1) dp += __shfl_xor(dp, d);
        if (lane == 0) sl_[wave][t] = dp * 0.03125f;
    }
    if (lane == 0) {
        float lm = -INFINITY;
        for (int t = 0; t < ns; t++) lm = fmaxf(lm, sl_[wave][t]);
        float den = 0.f, num = 0.f;
        for (int t = 0; t < ns; t++) {
            float e = __expf(sl_[wave][t] - lm);
            den += e;
            num += e * vmean[sm_[wave][t]];
        }
        out[row] = num / den;
    }
}

extern "C" void kernel_launch(void* const* d_in, const int* in_sizes, int n_in,
                              void* d_out, int out_size, void* d_ws, size_t ws_size,
                              hipStream_t stream) {
    const float* X  = (const float*)d_in[0];
    const float* Wq = (const float*)d_in[1];
    const float* Wk = (const float*)d_in[2];
    const float* Wv = (const float*)d_in[3];
    float* out = (float*)d_out;

    char* p = (char*)d_ws;
    auto alloc = [&](size_t bytes) -> void* {
        void* q = (void*)p;
        p += (bytes + 255) & ~(size_t)255;
        return q;
    };
    unsigned short* Wqhi = (unsigned short*)alloc((size_t)EMBED * EMBED * 2);
    unsigned short* Wqlo = (unsigned short*)alloc((size_t)EMBED * EMBED * 2);
    unsigned short* Wkhi = (unsigned short*)alloc((size_t)EMBED * EMBED * 2);
    unsigned short* Wklo = (unsigned short*)alloc((size_t)EMBED * EMBED * 2);
    unsigned short* MThi = (unsigned short*)alloc((size_t)EMBED * EMBED * 2);
    unsigned short* MTlo = (unsigned short*)alloc((size_t)EMBED * EMBED * 2);
    unsigned short* Xhi  = (unsigned short*)alloc((size_t)ROWS * EMBED * 2);
    unsigned short* Xlo  = (unsigned short*)alloc((size_t)ROWS * EMBED * 2);
    unsigned short* Thi  = (unsigned short*)alloc((size_t)ROWS * EMBED * 2);
    unsigned short* Tlo  = (unsigned short*)alloc((size_t)ROWS * EMBED * 2);
    float* wvbar = (float*)alloc(EMBED * 4);
    float* vmean = (float*)alloc((size_t)ROWS * 4);
    int*   cnt   = (int*)alloc((size_t)ROWS * 4);
    int2*  cand  = (int2*)alloc((size_t)ROWS * CAP * 8);

    k_wvbar<<<EMBED, 256, 0, stream>>>(Wv, wvbar);
    // Row splits of the ORIGINAL Wq/Wk (M contraction is over the contiguous output dim).
    // vmean/cnt args are scratch here (rows 0..1023; real run below overwrites all rows).
    k_xsplit_vmean<<<EMBED, 256, 0, stream>>>(Wq, wvbar, Wqhi, Wqlo, vmean, cnt);
    k_xsplit_vmean<<<EMBED, 256, 0, stream>>>(Wk, wvbar, Wkhi, Wklo, vmean, cnt);
    // M^T[b][a] = sum_n Wk[b][n]*Wq[a][n]
    k_gemm3<<<64, 256, 0, stream>>>(Wkhi, Wklo, Wqhi, Wqlo, MThi, MTlo);
    k_xsplit_vmean<<<ROWS, 256, 0, stream>>>(X, wvbar, Xhi, Xlo, vmean, cnt);  // real vmean + cnt=0
    k_gemm3<<<1024, 256, 0, stream>>>(Xhi, Xlo, MThi, MTlo, Thi, Tlo);         // T = X.M
    k_scan<<<1024, 512, 0, stream>>>(Thi, Xhi, cnt, cand);
    k_rescore<<<ROWS / 4, 256, 0, stream>>>(Thi, Tlo, X, vmean, cnt, cand, out);
}